// Round 5
// baseline (1270.502 us; speedup 1.0000x reference)
//
#include <hip/hip_runtime.h>

// B=8, N=HW=4096, D=512, I=256, DO=512
// ws (ushort offsets):
//   featT  @0        [b][n][c] bf16 (k0a->k1); overlaid by out1 (k3->k4)
//   featV  @16777216 [b][mt=64][c=512][m=64] bf16 (k0a->k3)
//   phi_n  @33554432 [b][n][i] bf16 normalized (k1->k3)
//   theta_n@41943040
//   wb_phi @50331648 [i][c] bf16, wb_th @50462720, weightT @50593792 [d][c]

typedef short s8v __attribute__((ext_vector_type(8)));
typedef float f4v __attribute__((ext_vector_type(4)));
typedef float f16v __attribute__((ext_vector_type(16)));

__device__ inline ushort f2bf(float x) {
  union { float f; unsigned u; } v; v.f = x;
  unsigned u = v.u + 0x7fff + ((v.u >> 16) & 1);
  return (ushort)(u >> 16);
}

// ---------- k0a: feat fp32 [b][c][m] -> featV blocked bf16 + featT bf16 ----
__global__ __launch_bounds__(256) void k0a(const float* __restrict__ feat,
                                           ushort* __restrict__ featT,
                                           ushort* __restrict__ featV) {
  int bid = blockIdx.x;
  int b = bid >> 9, cb = (bid >> 6) & 7, mt = bid & 63;
  int t = threadIdx.x;
  __shared__ ushort tile[64][72];

#pragma unroll
  for (int p = 0; p < 4; p++) {
    int ci = p * 16 + (t >> 4);
    int mi = (t & 15) * 4;
    float4 v = *(const float4*)&feat[((size_t)(b * 512 + cb * 64 + ci)) * 4096 + mt * 64 + mi];
    ushort4 u; u.x = f2bf(v.x); u.y = f2bf(v.y); u.z = f2bf(v.z); u.w = f2bf(v.w);
    *(ushort4*)&featV[((size_t)(b * 64 + mt) * 512 + cb * 64 + ci) * 64 + mi] = u;
    tile[ci][mi] = u.x; tile[ci][mi + 1] = u.y; tile[ci][mi + 2] = u.z; tile[ci][mi + 3] = u.w;
  }
  __syncthreads();
  int m = t >> 2, cs = (t & 3) * 16;
  ushort tmp[16];
#pragma unroll
  for (int j = 0; j < 16; j++) tmp[j] = tile[cs + j][m];
  ushort* dst = &featT[((size_t)(b * 4096 + mt * 64 + m)) * 512 + cb * 64 + cs];
  *(s8v*)dst = *(s8v*)&tmp[0];
  *(s8v*)(dst + 8) = *(s8v*)&tmp[8];
}

// ---------- k0b: cast phi_w / theta_w -> bf16 ------------------------------
__global__ __launch_bounds__(256) void k0b(const float* __restrict__ pw,
                                           const float* __restrict__ tw,
                                           ushort* __restrict__ wbp,
                                           ushort* __restrict__ wbt) {
  int bid = blockIdx.x;
  const float* src = (bid < 128) ? pw : tw;
  ushort* dst = (bid < 128) ? wbp : wbt;
  int idx = ((bid & 127) * 256 + threadIdx.x) * 4;
  float4 v = *(const float4*)&src[idx];
  ushort4 u; u.x = f2bf(v.x); u.y = f2bf(v.y); u.z = f2bf(v.z); u.w = f2bf(v.w);
  *(ushort4*)&dst[idx] = u;
}

// ---------- k0c: weight fp32 [c][d] -> weightT bf16 [d][c] -----------------
__global__ __launch_bounds__(256) void k0c(const float* __restrict__ w,
                                           ushort* __restrict__ wT) {
  int bid = blockIdx.x;
  int cb = bid >> 3, db = bid & 7;
  int t = threadIdx.x;
  __shared__ ushort tile[64][72];
#pragma unroll
  for (int p = 0; p < 4; p++) {
    int ci = p * 16 + (t >> 4);
    int di = (t & 15) * 4;
    float4 v = *(const float4*)&w[(size_t)(cb * 64 + ci) * 512 + db * 64 + di];
    tile[ci][di] = f2bf(v.x); tile[ci][di + 1] = f2bf(v.y);
    tile[ci][di + 2] = f2bf(v.z); tile[ci][di + 3] = f2bf(v.w);
  }
  __syncthreads();
  int d = t >> 2, cs = (t & 3) * 16;
  ushort tmp[16];
#pragma unroll
  for (int j = 0; j < 16; j++) tmp[j] = tile[cs + j][d];
  ushort* dst = &wT[(size_t)(db * 64 + d) * 512 + cb * 64 + cs];
  *(s8v*)dst = *(s8v*)&tmp[0];
  *(s8v*)(dst + 8) = *(s8v*)&tmp[8];
}

// ---------- k1: phi/theta MFMA GEMM + fused L2-normalize -> bf16 -----------
__global__ __launch_bounds__(256) void k1_gemm(
    const ushort* __restrict__ featT, const ushort* __restrict__ wbp,
    const ushort* __restrict__ wbt, ushort* __restrict__ phi_n,
    ushort* __restrict__ theta_n) {
  int bid = blockIdx.x;
  int b = bid & 7;
  int rest = bid >> 3;
  int half = rest & 1;
  int nt = rest >> 1;
  const ushort* wb = half ? wbt : wbp;
  ushort* dst = half ? theta_n : phi_n;
  int t = threadIdx.x;
  int lane = t & 63, w = t >> 6;
  int col = lane & 15, quad = lane >> 4;
  int n0 = nt * 64;

  const ushort* abase =
      featT + ((size_t)(b * 4096 + n0 + w * 16 + col)) * 512 + quad * 8;

  f4v acc[16];
#pragma unroll
  for (int i = 0; i < 16; i++) acc[i] = (f4v){0.f, 0.f, 0.f, 0.f};

#pragma unroll 2
  for (int kc = 0; kc < 16; kc++) {
    s8v a = *(const s8v*)(abase + kc * 32);
#pragma unroll
    for (int it = 0; it < 16; it++) {
      s8v bf = *(const s8v*)(wb + (size_t)(it * 16 + col) * 512 + kc * 32 + quad * 8);
      acc[it] = __builtin_amdgcn_mfma_f32_16x16x32_bf16(a, bf, acc[it], 0, 0, 0);
    }
  }
  float rinv[4];
#pragma unroll
  for (int reg = 0; reg < 4; reg++) {
    float ss = 0.f;
#pragma unroll
    for (int it = 0; it < 16; it++) ss += acc[it][reg] * acc[it][reg];
    ss += __shfl_xor(ss, 1); ss += __shfl_xor(ss, 2);
    ss += __shfl_xor(ss, 4); ss += __shfl_xor(ss, 8);
    rinv[reg] = rsqrtf(ss);
  }
#pragma unroll
  for (int it = 0; it < 16; it++) {
#pragma unroll
    for (int reg = 0; reg < 4; reg++) {
      dst[((size_t)(b * 4096 + n0 + w * 16 + quad * 4 + reg)) * 256 + it * 16 + col] =
          f2bf(acc[it][reg] * rinv[reg]);
    }
  }
}

// ---------- k3: flash attn, 32x32x16 MFMA, Q-tile 128, m-tile 64 -----------
// grid 256 = 8b(LSB) x 32qt, block 512 = 8 waves, 1 block/CU.
// QK: ng=w>>1 (32 q-rows), mh=w&1 (32-m half) -> S subtile 32x32 per wave.
// PV: nh=w>>2 (64 n-half), ch4=w&3 (128-c quarter) -> out 64n x 128c per wave.
__global__ __launch_bounds__(512, 2) void k3_attn(
    const ushort* __restrict__ phi_n, const ushort* __restrict__ theta_n,
    const ushort* __restrict__ featV, ushort* __restrict__ out1) {
  int bid = blockIdx.x;
  int b = bid & 7;
  int n0 = (bid >> 3) << 7;
  int t = threadIdx.x;
  int lane = t & 63, w = t >> 6;
  int l31 = lane & 31, h = lane >> 5;
  int ng = w >> 1, mh = w & 1;
  int ch4 = w & 3, nh = w >> 2;

  __shared__ __align__(16) ushort ks[2][16384];  // 64 rows x 256, 16B-chunk ^ (row&31)
  __shared__ __align__(16) ushort ps[2][8192];   // 128 rows x 64, chunk ^ (row&7)
  __shared__ float dred[2][128];

  const ushort* phb = phi_n + (size_t)b * 1048576;
  const ushort* thb = theta_n + (size_t)b * 1048576;
  const ushort* vbb = featV + (size_t)b * 2097152;

  // persistent Q A-frags (kc=0..7): A[n=l31][k=kc*16+h*8+j]
  const ushort* qbase = phb + (size_t)(n0 + ng * 32 + l31) * 256 + h * 8;
  s8v qf[8];
#pragma unroll
  for (int kc = 0; kc < 8; kc++) qf[kc] = *(const s8v*)(qbase + kc * 16);

  f16v acc[8];
#pragma unroll
  for (int i = 0; i < 8; i++)
#pragma unroll
    for (int j = 0; j < 16; j++) acc[i][j] = 0.f;
  float denp[16];
#pragma unroll
  for (int i = 0; i < 16; i++) denp[i] = 0.f;

  int srow = t >> 3, sg = t & 7;
  {  // stage K-tile 0
    const ushort* src = thb + (size_t)srow * 256 + sg * 32;
#pragma unroll
    for (int u = 0; u < 4; u++) {
      s8v v = *(const s8v*)(src + u * 8);
      int pos = (sg * 4 + u) ^ (srow & 31);
      *(s8v*)&ks[0][srow * 256 + pos * 8] = v;
    }
  }
  __syncthreads();

#pragma unroll 1
  for (int mt = 0; mt < 64; mt++) {
    int cur = mt & 1;
    const ushort* kcur = &ks[cur][0];
    ushort* pcur = &ps[cur][0];

    // 1. K prefetch (mt+1) -> regs
    s8v kreg[4];
    if (mt < 63) {
      const ushort* src = thb + (size_t)(mt + 1) * 16384 + (size_t)srow * 256 + sg * 32;
#pragma unroll
      for (int u = 0; u < 4; u++) kreg[u] = *(const s8v*)(src + u * 8);
    }
    // 2. Q A-frag reload kc=8..15 (L2-hot)
    s8v qf2[8];
#pragma unroll
    for (int j = 0; j < 8; j++) qf2[j] = *(const s8v*)(qbase + (8 + j) * 16);

    // 3. QK: S[32n x 32m] per wave, K=256
    f16v sv;
#pragma unroll
    for (int j = 0; j < 16; j++) sv[j] = 0.f;
    {
      const ushort* kb = kcur + (mh * 32 + l31) * 256;
#pragma unroll
      for (int kc = 0; kc < 8; kc++) {
        s8v bf = *(const s8v*)(kb + (((kc * 2 + h) ^ l31) * 8));
        sv = __builtin_amdgcn_mfma_f32_32x32x16_bf16(qf[kc], bf, sv, 0, 0, 0);
      }
#pragma unroll
      for (int kc = 8; kc < 16; kc++) {
        s8v bf = *(const s8v*)(kb + (((kc * 2 + h) ^ l31) * 8));
        sv = __builtin_amdgcn_mfma_f32_32x32x16_bf16(qf2[kc - 8], bf, sv, 0, 0, 0);
      }
    }
    // 4. exp (cos in [-1,1]), den accum, P -> ps[cur]
#pragma unroll
    for (int reg = 0; reg < 16; reg++) {
      float p = __expf(sv[reg]);
      denp[reg] += p;
      int n = ng * 32 + ((reg & 3) + 8 * (reg >> 2) + 4 * h);
      int m = mh * 32 + l31;
      pcur[n * 64 + (((m >> 3) ^ (n & 7)) * 8) + (m & 7)] = f2bf(p);
    }
    // 5. ks[next] <- kreg
    if (mt < 63) {
      ushort* kn = &ks[cur ^ 1][0];
#pragma unroll
      for (int u = 0; u < 4; u++) {
        int pos = (sg * 4 + u) ^ (srow & 31);
        *(s8v*)&kn[srow * 256 + pos * 8] = kreg[u];
      }
    }
    // 6. V B-frags kc=0,1 (full 128B line consumed within this mt)
    const ushort* vb = vbb + (size_t)mt * 32768;
    s8v vfA[8];
#pragma unroll
    for (int cs = 0; cs < 4; cs++) {
      const ushort* p = vb + (size_t)(ch4 * 128 + cs * 32 + l31) * 64 + h * 8;
      vfA[cs * 2 + 0] = *(const s8v*)(p);
      vfA[cs * 2 + 1] = *(const s8v*)(p + 16);
    }
    __syncthreads();  // ps[cur] + ks[next] ready

    // 7. PV: out[64n x 128c] per wave; A=P from LDS, B=V regs
    s8v vfB[4];
#pragma unroll
    for (int cs = 0; cs < 4; cs++)
      vfB[cs] = *(const s8v*)(vb + (size_t)(ch4 * 128 + cs * 32 + l31) * 64 + 32 + h * 8);
#pragma unroll
    for (int kc = 0; kc < 2; kc++) {
      s8v pa0 = *(const s8v*)(pcur + (nh * 64 + l31) * 64 + (((kc * 2 + h) ^ (l31 & 7)) * 8));
      s8v pa1 = *(const s8v*)(pcur + (nh * 64 + 32 + l31) * 64 + (((kc * 2 + h) ^ (l31 & 7)) * 8));
#pragma unroll
      for (int cs = 0; cs < 4; cs++) {
        acc[cs] = __builtin_amdgcn_mfma_f32_32x32x16_bf16(pa0, vfA[cs * 2 + kc], acc[cs], 0, 0, 0);
        acc[4 + cs] = __builtin_amdgcn_mfma_f32_32x32x16_bf16(pa1, vfA[cs * 2 + kc], acc[4 + cs], 0, 0, 0);
      }
    }
    s8v vfC[4];
#pragma unroll
    for (int cs = 0; cs < 4; cs++)
      vfC[cs] = *(const s8v*)(vb + (size_t)(ch4 * 128 + cs * 32 + l31) * 64 + 48 + h * 8);
    {
      s8v pa0 = *(const s8v*)(pcur + (nh * 64 + l31) * 64 + (((4 + h) ^ (l31 & 7)) * 8));
      s8v pa1 = *(const s8v*)(pcur + (nh * 64 + 32 + l31) * 64 + (((4 + h) ^ (l31 & 7)) * 8));
#pragma unroll
      for (int cs = 0; cs < 4; cs++) {
        acc[cs] = __builtin_amdgcn_mfma_f32_32x32x16_bf16(pa0, vfB[cs], acc[cs], 0, 0, 0);
        acc[4 + cs] = __builtin_amdgcn_mfma_f32_32x32x16_bf16(pa1, vfB[cs], acc[4 + cs], 0, 0, 0);
      }
    }
    {
      s8v pa0 = *(const s8v*)(pcur + (nh * 64 + l31) * 64 + (((6 + h) ^ (l31 & 7)) * 8));
      s8v pa1 = *(const s8v*)(pcur + (nh * 64 + 32 + l31) * 64 + (((6 + h) ^ (l31 & 7)) * 8));
#pragma unroll
      for (int cs = 0; cs < 4; cs++) {
        acc[cs] = __builtin_amdgcn_mfma_f32_32x32x16_bf16(pa0, vfC[cs], acc[cs], 0, 0, 0);
        acc[4 + cs] = __builtin_amdgcn_mfma_f32_32x32x16_bf16(pa1, vfC[cs], acc[4 + cs], 0, 0, 0);
      }
    }
  }

  // denominator: reduce across the 32 m-lanes, then across mh halves via LDS
#pragma unroll
  for (int reg = 0; reg < 16; reg++) {
    float d = denp[reg];
    d += __shfl_xor(d, 1); d += __shfl_xor(d, 2); d += __shfl_xor(d, 4);
    d += __shfl_xor(d, 8); d += __shfl_xor(d, 16);
    denp[reg] = d;
  }
  if (l31 == 0) {
#pragma unroll
    for (int reg = 0; reg < 16; reg++) {
      int n = ng * 32 + ((reg & 3) + 8 * (reg >> 2) + 4 * h);
      dred[mh][n] = denp[reg];
    }
  }
  __syncthreads();
  if (t < 128) dred[0][t] = 1.0f / (dred[0][t] + dred[1][t]);
  __syncthreads();

  // epilogue: store out1 bf16 [n][c]
#pragma unroll
  for (int nsub = 0; nsub < 2; nsub++) {
#pragma unroll
    for (int reg = 0; reg < 16; reg++) {
      int n = nh * 64 + nsub * 32 + ((reg & 3) + 8 * (reg >> 2) + 4 * h);
      float r = dred[0][n];
#pragma unroll
      for (int cs = 0; cs < 4; cs++) {
        int c = ch4 * 128 + cs * 32 + l31;
        out1[((size_t)(b * 4096 + n0 + n)) * 512 + c] = f2bf(acc[nsub * 4 + cs][reg] * r);
      }
    }
  }
}

// ---------- k4: out = relu((out1 @ weight)^T) stored [b][d][n] fp32 --------
__global__ __launch_bounds__(256) void k4_out(
    const ushort* __restrict__ out1, const ushort* __restrict__ wT,
    float* __restrict__ out) {
  int bid = blockIdx.x;
  int b = bid & 7;
  int rest = bid >> 3;
  int dt = rest & 7;
  int nt = rest >> 3;
  int t = threadIdx.x;
  int lane = t & 63, w = t >> 6;
  int col = lane & 15, quad = lane >> 4;
  int d0 = dt * 64;
  int n0 = nt * 256 + w * 64;

  f4v acc[16];
#pragma unroll
  for (int i = 0; i < 16; i++) acc[i] = (f4v){0.f, 0.f, 0.f, 0.f};

#pragma unroll 2
  for (int kc = 0; kc < 16; kc++) {
    s8v af[4], bf[4];
#pragma unroll
    for (int rs = 0; rs < 4; rs++)
      af[rs] = *(const s8v*)(wT + (size_t)(d0 + rs * 16 + col) * 512 + kc * 32 + quad * 8);
#pragma unroll
    for (int ct = 0; ct < 4; ct++)
      bf[ct] = *(const s8v*)(out1 + ((size_t)(b * 4096 + n0 + ct * 16 + col)) * 512 +
                             kc * 32 + quad * 8);
#pragma unroll
    for (int rs = 0; rs < 4; rs++)
#pragma unroll
      for (int ct = 0; ct < 4; ct++)
        acc[rs * 4 + ct] =
            __builtin_amdgcn_mfma_f32_16x16x32_bf16(af[rs], bf[ct], acc[rs * 4 + ct], 0, 0, 0);
  }
#pragma unroll
  for (int rs = 0; rs < 4; rs++) {
#pragma unroll
    for (int ct = 0; ct < 4; ct++) {
#pragma unroll
      for (int reg = 0; reg < 4; reg++) {
        int d = d0 + rs * 16 + quad * 4 + reg;
        int n = n0 + ct * 16 + col;
        out[((size_t)(b * 512 + d)) * 4096 + n] = fmaxf(acc[rs * 4 + ct][reg], 0.f);
      }
    }
  }
}

extern "C" void kernel_launch(void* const* d_in, const int* in_sizes, int n_in,
                              void* d_out, int out_size, void* d_ws, size_t ws_size,
                              hipStream_t stream) {
  const float* feat    = (const float*)d_in[0];
  const float* phi_w   = (const float*)d_in[1];
  const float* theta_w = (const float*)d_in[2];
  const float* weight  = (const float*)d_in[3];
  float* out = (float*)d_out;

  ushort* wsu = (ushort*)d_ws;
  ushort* featT   = wsu;                    // dead after k1 -> reused as out1
  ushort* featV   = wsu + 16777216;
  ushort* phi_n   = wsu + 33554432;
  ushort* theta_n = wsu + 41943040;
  ushort* wbp     = wsu + 50331648;
  ushort* wbt     = wsu + 50462720;
  ushort* weightT = wsu + 50593792;
  ushort* out1    = wsu;                    // overlays featT

  k0a<<<dim3(4096), dim3(256), 0, stream>>>(feat, featT, featV);
  k0b<<<dim3(256), dim3(256), 0, stream>>>(phi_w, theta_w, wbp, wbt);
  k0c<<<dim3(64), dim3(256), 0, stream>>>(weight, weightT);
  k1_gemm<<<dim3(1024), dim3(256), 0, stream>>>(featT, wbp, wbt, phi_n, theta_n);
  k3_attn<<<dim3(256), dim3(512), 0, stream>>>(phi_n, theta_n, featV, out1);
  k4_out<<<dim3(1024), dim3(256), 0, stream>>>(out1, weightT, out);
}